// Round 2
// baseline (719.467 us; speedup 1.0000x reference)
//
#include <hip/hip_runtime.h>
#include <stdint.h>

// Problem constants (fixed by setup_inputs): B=1, C=32, Z=64, Y=256, X=256
#define ZS 64
#define CS 32
#define YX 65536          // rays
#define RPB 64            // rays per block
#define FAR_DIST 1e10f
#define NOISE_LD 65       // padded leading dim for noise tile

// One block = 64 consecutive rays, 256 threads (4 waves).
// Phase 0: stage noise[64 rays][64 z] into LDS, fully coalesced float4 loads.
// Phase 1: wave 0, one ray per lane: sequential alpha/transmittance chain,
//          weights -> w_lds[z][ray]; acc_map store.
// Phase 2: lane = ray, 4 waves = 4 channel-groups of 8: composite features.
//          All global accesses have consecutive lanes -> consecutive floats.
__global__ __launch_bounds__(256) void rendernet_kernel(
    const float* __restrict__ feat,   // [C,Z,Y,X]
    const float* __restrict__ occ,    // [Z,Y,X] (leading B,1 dims collapsed)
    const float* __restrict__ zd,     // [Z]
    const float* __restrict__ noise,  // [N,Z]
    float* __restrict__ out)          // loss(1) + rgb(C*YX) + fe(C*YX) + acc(YX)
{
    __shared__ float w_lds[ZS * RPB];            // 16 KiB, [z][ray]
    __shared__ float noise_lds[RPB * NOISE_LD];  // 16.6 KiB, [ray][z] pad+1
    __shared__ float dist_s[ZS];

    const int t  = threadIdx.x;
    const int r0 = blockIdx.x * RPB;

    // ---- Phase 0: stage noise (block's 64x64 tile is contiguous in global) ----
    const float4* ng = reinterpret_cast<const float4*>(noise + (size_t)r0 * ZS);
    #pragma unroll
    for (int j = 0; j < 4; ++j) {
        int idx = j * 256 + t;            // 0..1023 float4s
        float4 v = ng[idx];               // lanes consecutive -> 1 KiB/instr
        int ray = idx >> 4;               // 16 float4 = 64 z per ray
        int zb  = (idx & 15) * 4;
        float* p = &noise_lds[ray * NOISE_LD + zb];
        p[0] = v.x; p[1] = v.y; p[2] = v.z; p[3] = v.w;
    }
    if (t < ZS) {
        float a = zd[t];
        dist_s[t] = (t < ZS - 1) ? (zd[t + 1] - a) : FAR_DIST;
    }
    __syncthreads();

    // ---- Phase 1: weights (sequential over z), wave 0 only ----
    if (t < RPB) {
        const int n = r0 + t;
        float T = 1.0f, wsum = 0.0f;
        #pragma unroll
        for (int z = 0; z < ZS; ++z) {
            float o   = occ[(size_t)z * YX + n];        // coalesced across lanes
            float ns  = noise_lds[t * NOISE_LD + z];    // (t+z)%32 banks: 2-way, free
            float raw = fmaxf(o + ns * 0.1f, 0.0f);
            float alpha = 1.0f - __expf(-raw * dist_s[z]);
            float w = alpha * T;
            w_lds[z * RPB + t] = w;
            wsum += w;
            T *= (1.0f - alpha + 1e-10f);
        }
        out[(size_t)1 + 2u * (size_t)CS * YX + n] = fminf(fmaxf(wsum, 0.0f), 1.0f);
        if (blockIdx.x == 0 && t == 0) out[0] = 0.0f;   // total_loss
    }
    __syncthreads();

    // ---- Phase 2: feature composite; lane = ray, wave = channel group ----
    const int ray = t & 63;
    const int g   = t >> 6;              // 0..3 -> channels g*8 .. g*8+7
    const int n   = r0 + ray;
    const float* fb = feat + (size_t)(g * 8) * ZS * YX + n;

    float acc[8];
    #pragma unroll
    for (int j = 0; j < 8; ++j) acc[j] = 0.0f;

    #pragma unroll 4
    for (int z = 0; z < ZS; ++z) {
        float w = w_lds[z * RPB + ray];  // bank = ray%32: 2-way, free
        #pragma unroll
        for (int j = 0; j < 8; ++j)
            acc[j] += w * fb[((size_t)j * ZS + z) * YX];  // 256B/instr coalesced
    }

    float* rgb = out + 1;
    float* fe  = out + 1 + (size_t)CS * YX;
    #pragma unroll
    for (int j = 0; j < 8; ++j) {
        const size_t o = (size_t)(g * 8 + j) * YX + n;   // lanes consecutive
        fe[o]  = acc[j];
        rgb[o] = 1.0f / (1.0f + __expf(-acc[j])) - 0.5f;
    }
}

extern "C" void kernel_launch(void* const* d_in, const int* in_sizes, int n_in,
                              void* d_out, int out_size, void* d_ws, size_t ws_size,
                              hipStream_t stream) {
    const float* feat  = (const float*)d_in[0];
    const float* occ   = (const float*)d_in[1];
    const float* zdist = (const float*)d_in[2];
    const float* noise = (const float*)d_in[3];
    float* out = (float*)d_out;

    rendernet_kernel<<<YX / RPB, 256, 0, stream>>>(feat, occ, zdist, noise, out);
}